// Round 7
// baseline (61.078 us; speedup 1.0000x reference)
//
#include <hip/hip_runtime.h>

#define NB 524288
#define NC 32
#define NQ 16          // center pairs
#define EPSV 1e-4f
#define DTB 0.12f      // DT * BETA
#define CLAMPV 3.0f
#define NSTEPS 4

typedef float f32x2 __attribute__((ext_vector_type(2)));

__device__ __forceinline__ f32x2 pk_fma(f32x2 a, f32x2 b, f32x2 c) {
    return __builtin_elementwise_fma(a, b, c);
}

// ws layout (floats):
//   [0, 256)   : ct[q*16 + d*2 + {0,1}] = {centers[2q][d], centers[2q+1][d]}
//   [256, 320) : per q: {|c_2q|^2+EPS, |c_2q+1|^2+EPS, mu_2q, mu_2q+1}
__global__ void prep_kernel(const float* __restrict__ centers,
                            const float* __restrict__ mus,
                            float* __restrict__ ws) {
    int q = threadIdx.x;
    if (q < NQ) {
        float n0 = EPSV, n1 = EPSV;
        #pragma unroll
        for (int d = 0; d < 8; ++d) {
            float a = centers[(2 * q) * 8 + d];
            float b = centers[(2 * q + 1) * 8 + d];
            ws[q * 16 + d * 2 + 0] = a;
            ws[q * 16 + d * 2 + 1] = b;
            n0 = fmaf(a, a, n0);
            n1 = fmaf(b, b, n1);
        }
        ws[256 + q * 4 + 0] = n0;
        ws[256 + q * 4 + 1] = n1;
        ws[256 + q * 4 + 2] = mus[2 * q];
        ws[256 + q * 4 + 3] = mus[2 * q + 1];
    }
}

__global__ __launch_bounds__(256, 8) void pm_kernel(
    const float* __restrict__ z_in,
    const float* __restrict__ ws,
    float* __restrict__ out)
{
    const int i = blockIdx.x * 256 + threadIdx.x;

    const float4* zp = (const float4*)z_in;
    float4 a0 = zp[(size_t)i * 2], a1 = zp[(size_t)i * 2 + 1];
    // z kept as splat pairs {z_d, z_d} so all center math is packed
    f32x2 zs[8] = {{a0.x, a0.x}, {a0.y, a0.y}, {a0.z, a0.z}, {a0.w, a0.w},
                   {a1.x, a1.x}, {a1.y, a1.y}, {a1.z, a1.z}, {a1.w, a1.w}};

    // Wave-uniform reads -> s_load of consecutive SGPR pairs.
    const f32x2* ct = (const f32x2*)ws;          // ct[q*8 + d] = {c_d, c'_d}
    const f32x2* bm = (const f32x2*)(ws + 256);  // bm[q*2] = bb2, bm[q*2+1] = mu2

    #pragma unroll 1
    for (int s = 0; s < NSTEPS; ++s) {
        // zz in both lanes
        f32x2 zz2 = zs[0] * zs[0];
        #pragma unroll
        for (int d = 1; d < 8; ++d) zz2 = pk_fma(zs[d], zs[d], zz2);

        f32x2 n2  = {0.f, 0.f};
        f32x2 sw2 = {0.f, 0.f};
        f32x2 gc[8] = {{0.f,0.f},{0.f,0.f},{0.f,0.f},{0.f,0.f},
                       {0.f,0.f},{0.f,0.f},{0.f,0.f},{0.f,0.f}};

        #pragma unroll
        for (int q = 0; q < NQ; ++q) {
            // packed dot: lane0 accumulates z.c_{2q}, lane1 z.c_{2q+1}
            f32x2 dot2 = zs[0] * ct[q * 8 + 0];
            #pragma unroll
            for (int d = 1; d < 8; ++d)
                dot2 = pk_fma(zs[d], ct[q * 8 + d], dot2);

            f32x2 bb2 = bm[q * 2 + 0];
            f32x2 mu2 = bm[q * 2 + 1];
            const f32x2 m2 = {-2.0f, -2.0f};
            f32x2 r2 = pk_fma(m2, dot2, zz2 + bb2);   // no horizontal reduce!

            f32x2 rinv2;
            rinv2.x = __builtin_amdgcn_rsqf(r2.x);    // v_rsq_f32 x2
            rinv2.y = __builtin_amdgcn_rsqf(r2.y);

            n2 = pk_fma(mu2, rinv2, n2);              // n partials, packed
            f32x2 t  = mu2 * rinv2;
            f32x2 ri = rinv2 * rinv2;
            f32x2 w3 = t * ri;                        // mu / r^3, packed
            sw2 = sw2 + w3;
            #pragma unroll
            for (int d = 0; d < 8; ++d)
                gc[d] = pk_fma(w3, ct[q * 8 + d], gc[d]);
        }

        float n  = 1.0f + n2.x + n2.y;
        float sw = sw2.x + sw2.y;
        float scale = DTB * __builtin_amdgcn_rcpf(n); // v_rcp_f32
        #pragma unroll
        for (int d = 0; d < 8; ++d) {
            float zd = zs[d].x;
            float g  = fmaf(-sw, zd, gc[d].x + gc[d].y);
            float zn = fmaf(scale, g, zd);
            zn = fminf(fmaxf(zn, -CLAMPV), CLAMPV);
            zs[d] = (f32x2){zn, zn};
        }
    }

    float4 o0 = {zs[0].x, zs[1].x, zs[2].x, zs[3].x};
    float4 o1 = {zs[4].x, zs[5].x, zs[6].x, zs[7].x};
    float4* op = (float4*)out;
    op[(size_t)i * 2]     = o0;
    op[(size_t)i * 2 + 1] = o1;
}

extern "C" void kernel_launch(void* const* d_in, const int* in_sizes, int n_in,
                              void* d_out, int out_size, void* d_ws, size_t ws_size,
                              hipStream_t stream) {
    const float* z       = (const float*)d_in[0];
    const float* centers = (const float*)d_in[1];
    const float* mus     = (const float*)d_in[2];
    float* out           = (float*)d_out;
    float* ws            = (float*)d_ws;

    prep_kernel<<<1, 64, 0, stream>>>(centers, mus, ws);
    pm_kernel<<<NB / 256, 256, 0, stream>>>(z, ws, out);
}